// Round 7
// baseline (878.716 us; speedup 1.0000x reference)
//
#include <hip/hip_runtime.h>
#include <math.h>

#define N_CFG 400000
#define E_CFG 1600000
#define N_FUNC 8000
#define N_EXT 1600
#define N_FCG (N_FUNC + N_EXT)
#define E_FCG 80000
#define NBATCH 8
#define VOCAB 10002

typedef unsigned int uint32;
typedef unsigned long long ull;
typedef __attribute__((ext_vector_type(8))) short bf16x8;
typedef __attribute__((ext_vector_type(4))) float f32x4;

// ---------- bf16 helpers ----------
__device__ __forceinline__ float bf2f(unsigned short u){
  union { unsigned int i; float f; } v; v.i = ((unsigned int)u) << 16; return v.f;
}
__device__ __forceinline__ float bflo(unsigned int u){
  union { unsigned int i; float f; } v; v.i = u << 16; return v.f;
}
__device__ __forceinline__ float bfhi(unsigned int u){
  union { unsigned int i; float f; } v; v.i = u & 0xffff0000u; return v.f;
}
__device__ __forceinline__ unsigned short f2bf(float f){
  union { float f; unsigned int i; } v; v.f = f;
  unsigned int i = v.i;
  unsigned int r = (i + 0x7fffu + ((i >> 16) & 1u)) >> 16;  // RNE
  return (unsigned short)r;
}
__device__ __forceinline__ unsigned int packbf(float x, float y){
  return (unsigned int)f2bf(x) | (((unsigned int)f2bf(y)) << 16);
}
__device__ __forceinline__ int lowerb(const int* __restrict__ a, int n, int key){
  int lo = 0, hi = n;
  while (lo < hi){ int mid = (lo + hi) >> 1; if (a[mid] < key) lo = mid + 1; else hi = mid; }
  return lo;
}

// ---------- k_init: flag + all conversions + zeroing, one kernel ----------
struct InitParams {
  const void *cfg_x, *W1, *W2, *Wf, *b1, *b2, *bfv, *emb, *Wp1, *bp1, *Wp2, *bp2, *Wp3, *bp3;
  unsigned short *cx, *cW1t, *cW2t, *cWft, *cb1, *cb2, *cbf, *cemb, *cWp1, *cbp1, *cWp2, *cbp2, *cWp3, *cbp3;
  uint32 *cnt_cfg; ull* state; uint32* ticket; uint32* done; int* flag;
};

#define CVLOOP(srcp, dstp, nn) \
  for (long i = gid; i < (nn); i += gsz) \
    (dstp)[i] = isbf ? ((const unsigned short*)(srcp))[i] : f2bf(((const float*)(srcp))[i]);

__global__ __launch_bounds__(256)
void k_init(InitParams P){
  __shared__ int viol;
  int tid = threadIdx.x;
  if (tid == 0) viol = 0;
  __syncthreads();
  const unsigned int* eu = (const unsigned int*)P.emb;
  int my = 0;
  for (int i = tid; i < 1024; i += 256){
    unsigned int lo = eu[i] & 0xffffu;
    unsigned int ex = (lo >> 7) & 0xffu;
    if (!((ex == 0u) || (ex >= 80u && ex <= 127u))) my++;
  }
  atomicAdd(&viol, my);
  __syncthreads();
  int isbf = (viol < 100) ? 1 : 0;      // 1 = inputs bf16-packed, 0 = fp32
  long gid = (long)blockIdx.x * 256 + tid;
  long gsz = (long)gridDim.x * 256;
  if (gid == 0){ *P.flag = isbf; *P.ticket = 0u; *P.done = 0u; }
  for (long i = gid; i < 400; i += gsz) P.state[i] = 0ULL;
  uint4 z4 = {0u,0u,0u,0u};
  for (long i = gid; i < N_CFG/4; i += gsz) ((uint4*)P.cnt_cfg)[i] = z4;
  // cfg_x -> canonical bf16 (8 elems / item)
  long nx8 = (long)N_CFG * 64 / 8;
  for (long i = gid; i < nx8; i += gsz){
    uint4 o;
    if (isbf){
      o = ((const uint4*)P.cfg_x)[i];
    } else {
      const float4* f = (const float4*)P.cfg_x + i * 2;
      float4 f0 = f[0], f1 = f[1];
      o.x = packbf(f0.x, f0.y); o.y = packbf(f0.z, f0.w);
      o.z = packbf(f1.x, f1.y); o.w = packbf(f1.z, f1.w);
    }
    ((uint4*)P.cx)[i] = o;
  }
  CVLOOP(P.emb, P.cemb, (long)VOCAB * 128);
  // W transposes (K x 128 -> 128 x K)
  for (long i = gid; i < 64 * 128; i += gsz){
    int k = i >> 7, n = i & 127;
    unsigned short v = isbf ? ((const unsigned short*)P.W1)[i] : f2bf(((const float*)P.W1)[i]);
    P.cW1t[n * 64 + k] = v;
  }
  for (long i = gid; i < 128 * 128; i += gsz){
    int k = i >> 7, n = i & 127;
    unsigned short v = isbf ? ((const unsigned short*)P.W2)[i] : f2bf(((const float*)P.W2)[i]);
    P.cW2t[n * 128 + k] = v;
    unsigned short w = isbf ? ((const unsigned short*)P.Wf)[i] : f2bf(((const float*)P.Wf)[i]);
    P.cWft[n * 128 + k] = w;
  }
  CVLOOP(P.b1, P.cb1, 128); CVLOOP(P.b2, P.cb2, 128); CVLOOP(P.bfv, P.cbf, 128);
  CVLOOP(P.Wp1, P.cWp1, 8192); CVLOOP(P.bp1, P.cbp1, 64);
  CVLOOP(P.Wp2, P.cWp2, 2048); CVLOOP(P.bp2, P.cbp2, 32);
  CVLOOP(P.Wp3, P.cWp3, 32);   CVLOOP(P.bp3, P.cbp3, 1);
}

// ---------- degree count ----------
__global__ void k_count(const int* __restrict__ idx, int n, uint32* __restrict__ cnt){
  int i = blockIdx.x * 256 + threadIdx.x;
  if (i < n) atomicAdd(&cnt[idx[i]], 1u);
}

// ---------- single-kernel exclusive scan (decoupled lookback, ticket-ordered) ----------
__global__ __launch_bounds__(256)
void k_scan_lb(const uint32* __restrict__ cnt, int n,
               uint32* __restrict__ off, uint32* __restrict__ cur, float* __restrict__ dis,
               ull* __restrict__ state, uint32* __restrict__ ticket){
  __shared__ uint32 s[256];
  __shared__ uint32 tshare, bshare;
  int tid = threadIdx.x;
  if (tid == 0) tshare = atomicAdd(ticket, 1u);
  __syncthreads();
  uint32 t = tshare;
  int base = (int)t * 1024 + tid * 4;
  uint32 v0 = (base+0<n)?cnt[base+0]:0u, v1 = (base+1<n)?cnt[base+1]:0u;
  uint32 v2 = (base+2<n)?cnt[base+2]:0u, v3 = (base+3<n)?cnt[base+3]:0u;
  uint32 tsum = v0+v1+v2+v3, x = tsum;
  s[tid] = x; __syncthreads();
  for (int o = 1; o < 256; o <<= 1){
    uint32 y = (tid >= o) ? s[tid - o] : 0u;
    __syncthreads();
    x += y; s[tid] = x; __syncthreads();
  }
  uint32 total = s[255];
  if (tid == 0){
    if (t == 0){
      atomicExch(&state[0], (2ULL << 32) | (ull)total);
      bshare = 0u;
    } else {
      atomicExch(&state[t], (1ULL << 32) | (ull)total);
      uint32 run = 0; int idx = (int)t - 1;
      while (true){
        ull sv = atomicAdd(&state[idx], 0ULL);
        uint32 st = (uint32)(sv >> 32);
        if (st == 0u){ __builtin_amdgcn_s_sleep(1); continue; }
        run += (uint32)sv;
        if (st == 2u) break;
        idx--;
      }
      atomicExch(&state[t], (2ULL << 32) | (ull)(run + total));
      bshare = run;
    }
  }
  __syncthreads();
  uint32 run = bshare + (x - tsum);
  if (base+0<n){ off[base+0]=run; cur[base+0]=run; dis[base+0]=rsqrtf((float)v0+1.f); } run+=v0;
  if (base+1<n){ off[base+1]=run; cur[base+1]=run; dis[base+1]=rsqrtf((float)v1+1.f); } run+=v1;
  if (base+2<n){ off[base+2]=run; cur[base+2]=run; dis[base+2]=rsqrtf((float)v2+1.f); } run+=v2;
  if (base+3<n){ off[base+3]=run; cur[base+3]=run; dis[base+3]=rsqrtf((float)v3+1.f); }
}

// ---------- windowed CSR fill (stores land in a contiguous L2-resident region) ----------
__global__ void k_fill_win(const int* __restrict__ edges, int E,
                           uint32* __restrict__ cur, int* __restrict__ sorted,
                           int lo, int hi){
  int e = blockIdx.x * 256 + threadIdx.x;
  if (e >= E) return;
  int c = edges[E + e];
  if (c < lo || c >= hi) return;
  int r = edges[e];
  uint32 p = atomicAdd(&cur[c], 1u);
  sorted[p] = r;
}

// ---------- dis-weighted aggregation: Z[n] = sum_in dis[r]*x[r] + dis[n]*x[n] ----------
// LPN lanes per node, each lane handles 8 dims (uint4 of bf16). 4-way edge unroll.
#define ACCD(u, d) { \
  a[0] = fmaf(d, bflo(u.x), a[0]); a[1] = fmaf(d, bfhi(u.x), a[1]); \
  a[2] = fmaf(d, bflo(u.y), a[2]); a[3] = fmaf(d, bfhi(u.y), a[3]); \
  a[4] = fmaf(d, bflo(u.z), a[4]); a[5] = fmaf(d, bfhi(u.z), a[5]); \
  a[6] = fmaf(d, bflo(u.w), a[6]); a[7] = fmaf(d, bfhi(u.w), a[7]); }

template<int LPN>
__global__ __launch_bounds__(256)
void k_aggZ(const uint4* __restrict__ x4, const uint32* __restrict__ off,
            const uint32* __restrict__ cnt, const int* __restrict__ sorted,
            const float* __restrict__ dis, uint4* __restrict__ z4, int n){
  int tid = threadIdx.x;
  int grp = tid / LPN, sub = tid % LPN;
  int node = blockIdx.x * (256 / LPN) + grp;
  if (node >= n) return;
  uint32 o = off[node], c = cnt[node];
  float a[8] = {0.f,0.f,0.f,0.f,0.f,0.f,0.f,0.f};
  uint32 j = 0;
  for (; j + 3 < c; j += 4){
    int r0 = sorted[o+j], r1 = sorted[o+j+1], r2 = sorted[o+j+2], r3 = sorted[o+j+3];
    float d0 = dis[r0], d1 = dis[r1], d2 = dis[r2], d3 = dis[r3];
    uint4 u0 = x4[(long)r0 * LPN + sub];
    uint4 u1 = x4[(long)r1 * LPN + sub];
    uint4 u2 = x4[(long)r2 * LPN + sub];
    uint4 u3 = x4[(long)r3 * LPN + sub];
    ACCD(u0, d0); ACCD(u1, d1); ACCD(u2, d2); ACCD(u3, d3);
  }
  for (; j < c; j++){
    int r = sorted[o + j];
    float d = dis[r];
    uint4 u = x4[(long)r * LPN + sub];
    ACCD(u, d);
  }
  {
    float d = dis[node];
    uint4 u = x4[(long)node * LPN + sub];
    ACCD(u, d);
  }
  uint4 ov;
  ov.x = packbf(a[0], a[1]); ov.y = packbf(a[2], a[3]);
  ov.z = packbf(a[4], a[5]); ov.w = packbf(a[6], a[7]);
  z4[(long)node * LPN + sub] = ov;
}

// ---------- MFMA GEMM + fused epilogue: out = relu(dis[r]*(Z@W) + bias), N=128 ----------
template<int K>
__global__ __launch_bounds__(256)
void k_gemm_relu(const unsigned short* __restrict__ X, const unsigned short* __restrict__ Wt,
                 const float* __restrict__ dis, const unsigned short* __restrict__ bias,
                 unsigned short* __restrict__ out){
  const int KP = K + 8;
  __shared__ unsigned short Xs[64 * (K + 8)];
  __shared__ unsigned short Ws[128 * (K + 8)];
  int tid = threadIdx.x;
  long row0 = (long)blockIdx.x * 64;
  {
    int n = tid >> 1, half = tid & 1;
    const uint4* src = (const uint4*)(Wt + n * K) + half * (K / 16);
    uint4* dst = (uint4*)(Ws + n * KP) + half * (K / 16);
    #pragma unroll
    for (int i = 0; i < K / 16; i++) dst[i] = src[i];
  }
  {
    int r = tid >> 2, part = tid & 3;
    const uint4* src = (const uint4*)(X + (row0 + r) * K) + part * (K / 32);
    uint4* dst = (uint4*)(Xs + r * KP) + part * (K / 32);
    #pragma unroll
    for (int i = 0; i < K / 32; i++) dst[i] = src[i];
  }
  __syncthreads();

  int w = tid >> 6, lane = tid & 63, m = lane & 15, q = lane >> 4;
  f32x4 acc[8];
  #pragma unroll
  for (int t = 0; t < 8; t++) acc[t] = (f32x4){0.f, 0.f, 0.f, 0.f};
  const unsigned short* Arow = &Xs[(w * 16 + m) * KP + q * 8];
  const unsigned short* Bbase = &Ws[m * KP + q * 8];
  #pragma unroll
  for (int kc = 0; kc < K; kc += 32){
    bf16x8 a = *(const bf16x8*)(Arow + kc);
    #pragma unroll
    for (int t = 0; t < 8; t++){
      bf16x8 b = *(const bf16x8*)(Bbase + t * 16 * KP + kc);
      acc[t] = __builtin_amdgcn_mfma_f32_16x16x32_bf16(a, b, acc[t], 0, 0, 0);
    }
  }
  float d[4];
  #pragma unroll
  for (int r = 0; r < 4; r++) d[r] = dis[row0 + w * 16 + q * 4 + r];
  #pragma unroll
  for (int t = 0; t < 8; t++){
    float bc = bf2f(bias[t * 16 + m]);
    #pragma unroll
    for (int r = 0; r < 4; r++){
      long grow = row0 + w * 16 + q * 4 + r;
      out[grow * 128 + t * 16 + m] = f2bf(fmaxf(fmaf(d[r], acc[t][r], bc), 0.f));
    }
  }
}

// ---------- per-function mean pool, segment bounds via binary search ----------
__global__ void k_pool_mean(const unsigned int* __restrict__ x2, const int* __restrict__ n2f,
                            unsigned int* __restrict__ pooled2){
  int f = blockIdx.x; int t = threadIdx.x;   // 64 threads
  int s = lowerb(n2f, N_CFG, f);
  int e = lowerb(n2f, N_CFG, f + 1);
  float sx = 0.f, sy = 0.f;
  for (int j = s; j < e; j++){
    unsigned int u = x2[(long)j * 64 + t];
    sx += bflo(u); sy += bfhi(u);
  }
  int c = e - s;
  float inv = 1.0f / (float)((c > 0) ? c : 1);
  pooled2[(long)f * 64 + t] = packbf(sx * inv, sy * inv);
}

// ---------- FCG node features ----------
__global__ void k_assemble(const unsigned int* __restrict__ pooled2, const unsigned int* __restrict__ emb2,
                           const int* __restrict__ src, const int* __restrict__ isext,
                           unsigned int* __restrict__ fx2){
  int i = blockIdx.x; int t = threadIdx.x;
  int s = src[i];
  unsigned int v;
  if (isext[i] == 1){
    int idx = s; if (idx < 0) idx = 0; if (idx > VOCAB - 1) idx = VOCAB - 1;
    v = emb2[(long)idx * 64 + t];
  } else {
    int f = s; if (f < 0) f = 0; if (f > N_FUNC - 1) f = N_FUNC - 1;
    v = pooled2[(long)f * 64 + t];
  }
  fx2[(long)i * 64 + t] = v;
}

// ---------- whole FCG CSR (count + scan + dis + fill) in one block, LDS-resident ----------
__global__ __launch_bounds__(1024)
void k_fcg_csr(const int* __restrict__ edges, uint32* __restrict__ cnt_f,
               uint32* __restrict__ off_f, float* __restrict__ dis_f,
               int* __restrict__ sorted_f){
  __shared__ uint32 scnt[N_FCG];
  __shared__ uint32 stmp[1024];
  int tid = threadIdx.x;
  for (int i = tid; i < N_FCG; i += 1024) scnt[i] = 0u;
  __syncthreads();
  for (int e = tid; e < E_FCG; e += 1024) atomicAdd(&scnt[edges[E_FCG + e]], 1u);
  __syncthreads();
  // write counts + dis, scan into off
  uint32 local[10], s = 0;
  #pragma unroll
  for (int k = 0; k < 10; k++){
    int idx = tid * 10 + k;
    uint32 v = (idx < N_FCG) ? scnt[idx] : 0u;
    local[k] = s; s += v;
  }
  uint32 x = s;
  stmp[tid] = x; __syncthreads();
  for (int o = 1; o < 1024; o <<= 1){
    uint32 y = (tid >= o) ? stmp[tid - o] : 0u;
    __syncthreads();
    x += y; stmp[tid] = x; __syncthreads();
  }
  uint32 excl = x - s;
  uint32 offv[10];
  #pragma unroll
  for (int k = 0; k < 10; k++){
    int idx = tid * 10 + k;
    if (idx < N_FCG){
      uint32 cv = scnt[idx];
      uint32 ov = excl + local[k];
      offv[k] = ov;
      cnt_f[idx] = cv;
      off_f[idx] = ov;
      dis_f[idx] = rsqrtf((float)cv + 1.0f);
    }
  }
  __syncthreads();
  #pragma unroll
  for (int k = 0; k < 10; k++){
    int idx = tid * 10 + k;
    if (idx < N_FCG) scnt[idx] = offv[k];   // scnt becomes "cur"
  }
  __syncthreads();
  for (int e = tid; e < E_FCG; e += 1024){
    int c = edges[E_FCG + e];
    int r = edges[e];
    uint32 p = atomicAdd(&scnt[c], 1u);
    sorted_f[p] = r;
  }
}

// ---------- per-binary mean pool + head (last-block pattern, device-scope atomics) ----------
__global__ __launch_bounds__(256)
void k_pool_head(const uint4* __restrict__ y4, const int* __restrict__ batch,
                 float* __restrict__ G, uint32* __restrict__ done,
                 const unsigned short* __restrict__ Wp1, const unsigned short* __restrict__ bp1,
                 const unsigned short* __restrict__ Wp2, const unsigned short* __restrict__ bp2,
                 const unsigned short* __restrict__ Wp3, const unsigned short* __restrict__ bp3,
                 void* __restrict__ outp, const int* __restrict__ flag){
  __shared__ float red[16][128];
  __shared__ uint32 tick;
  int b = blockIdx.x, tid = threadIdx.x;
  int s = lowerb(batch, N_FCG, b);
  int e = lowerb(batch, N_FCG, b + 1);
  int grp = tid >> 4, sub = tid & 15;
  float a[8] = {0.f,0.f,0.f,0.f,0.f,0.f,0.f,0.f};
  for (int i = s + grp; i < e; i += 16){
    uint4 u = y4[(long)i * 16 + sub];
    a[0] += bflo(u.x); a[1] += bfhi(u.x);
    a[2] += bflo(u.y); a[3] += bfhi(u.y);
    a[4] += bflo(u.z); a[5] += bfhi(u.z);
    a[6] += bflo(u.w); a[7] += bfhi(u.w);
  }
  #pragma unroll
  for (int i = 0; i < 8; i++) red[grp][sub * 8 + i] = a[i];
  __syncthreads();
  int c = e - s;
  float inv = 1.0f / (float)((c > 0) ? c : 1);
  if (tid < 128){
    float t2 = 0.f;
    #pragma unroll
    for (int g = 0; g < 16; g++) t2 += red[g][tid];
    atomicExch((unsigned int*)&G[b * 128 + tid], __float_as_uint(t2 * inv)); // device-coherent write
  }
  __threadfence();
  __syncthreads();
  if (tid == 0) tick = atomicAdd(done, 1u);
  __syncthreads();
  if (tick != NBATCH - 1) return;
  // last block: projection head
  __shared__ float Gs[1024];
  __shared__ float H1[512];
  __shared__ float H2[256];
  for (int i = tid; i < 1024; i += 256)
    Gs[i] = __uint_as_float(atomicAdd((unsigned int*)&G[i], 0u));  // device-coherent read
  __syncthreads();
  for (int i = tid; i < 512; i += 256){
    int bb = i >> 6, j = i & 63;
    float acc = bf2f(bp1[j]);
    for (int d = 0; d < 128; d++) acc = fmaf(Gs[bb * 128 + d], bf2f(Wp1[d * 64 + j]), acc);
    H1[i] = fmaxf(acc, 0.f);
  }
  __syncthreads();
  {
    int bb = tid >> 5, j = tid & 31;
    float acc = bf2f(bp2[j]);
    for (int d = 0; d < 64; d++) acc = fmaf(H1[bb * 64 + d], bf2f(Wp2[d * 32 + j]), acc);
    H2[tid] = fmaxf(acc, 0.f);
  }
  __syncthreads();
  if (tid < 8){
    float acc = bf2f(bp3[0]);
    for (int d = 0; d < 32; d++) acc = fmaf(H2[tid * 32 + d], bf2f(Wp3[d]), acc);
    float sg = 1.f / (1.f + __expf(-acc));
    if (*flag) ((unsigned short*)outp)[tid] = f2bf(sg);
    else       ((float*)outp)[tid] = sg;
  }
}

extern "C" void kernel_launch(void* const* d_in, const int* in_sizes, int n_in,
                              void* d_out, int out_size, void* d_ws, size_t ws_size,
                              hipStream_t stream){
  const void* cfg_x     = d_in[0];
  const int*  cfg_edges = (const int*)d_in[1];
  const int*  node2func = (const int*)d_in[2];
  const int*  fcg_edges = (const int*)d_in[3];
  const int*  fcg_batch = (const int*)d_in[4];
  const int*  fcg_src   = (const int*)d_in[5];
  const int*  fcg_isext = (const int*)d_in[6];

  char* p = (char*)d_ws;
  auto carve = [&](size_t bytes)->char* {
    char* r = p; p += (bytes + 255) & ~(size_t)255; return r;
  };
  unsigned short* A   = (unsigned short*)carve((size_t)N_CFG * 128 * 2);  // Z1 / Z2
  unsigned short* Bx  = (unsigned short*)carve((size_t)N_CFG * 128 * 2);  // x2 / x3
  unsigned short* cx  = (unsigned short*)carve((size_t)N_CFG * 64 * 2);   // canonical bf16 cfg_x
  uint32* cnt_cfg = (uint32*)carve((size_t)N_CFG * 4);
  uint32* off_cfg = (uint32*)carve((size_t)N_CFG * 4);
  uint32* cur_cfg = (uint32*)carve((size_t)N_CFG * 4);
  float*  dis_cfg = (float*) carve((size_t)N_CFG * 4);
  int*    sorted_cfg = (int*)carve((size_t)E_CFG * 4);
  ull*    state = (ull*)carve(400 * 8);
  uint32* ticket = (uint32*)carve(256);
  uint32* done   = (uint32*)carve(256);
  int*    flag   = (int*)carve(256);
  unsigned int* pooled2 = (unsigned int*)carve((size_t)N_FUNC * 64 * 4);
  unsigned int* fx2     = (unsigned int*)carve((size_t)N_FCG * 64 * 4);
  unsigned short* Zf    = (unsigned short*)carve((size_t)N_FCG * 128 * 2);
  unsigned short* yf    = (unsigned short*)carve((size_t)N_FCG * 128 * 2);
  uint32* cnt_f = (uint32*)carve(N_FCG * 4);
  uint32* off_f = (uint32*)carve(N_FCG * 4);
  float*  dis_f = (float*) carve(N_FCG * 4);
  int*    sorted_f = (int*)carve(E_FCG * 4);
  float*  G = (float*)carve(8 * 128 * 4);
  unsigned short* cW1t = (unsigned short*)carve(128 * 64 * 2);
  unsigned short* cb1  = (unsigned short*)carve(128 * 2);
  unsigned short* cW2t = (unsigned short*)carve(128 * 128 * 2);
  unsigned short* cb2  = (unsigned short*)carve(128 * 2);
  unsigned short* cemb = (unsigned short*)carve((size_t)VOCAB * 128 * 2);
  unsigned short* cWft = (unsigned short*)carve(128 * 128 * 2);
  unsigned short* cbf  = (unsigned short*)carve(128 * 2);
  unsigned short* cWp1 = (unsigned short*)carve(128 * 64 * 2);
  unsigned short* cbp1 = (unsigned short*)carve(64 * 2);
  unsigned short* cWp2 = (unsigned short*)carve(64 * 32 * 2);
  unsigned short* cbp2 = (unsigned short*)carve(32 * 2);
  unsigned short* cWp3 = (unsigned short*)carve(32 * 2);
  unsigned short* cbp3 = (unsigned short*)carve(2 * 2);

  // 1) init: flag + conversions + zeroing
  InitParams P;
  P.cfg_x = cfg_x; P.W1 = d_in[7]; P.W2 = d_in[9]; P.Wf = d_in[12];
  P.b1 = d_in[8]; P.b2 = d_in[10]; P.bfv = d_in[13]; P.emb = d_in[11];
  P.Wp1 = d_in[14]; P.bp1 = d_in[15]; P.Wp2 = d_in[16]; P.bp2 = d_in[17];
  P.Wp3 = d_in[18]; P.bp3 = d_in[19];
  P.cx = cx; P.cW1t = cW1t; P.cW2t = cW2t; P.cWft = cWft;
  P.cb1 = cb1; P.cb2 = cb2; P.cbf = cbf; P.cemb = cemb;
  P.cWp1 = cWp1; P.cbp1 = cbp1; P.cWp2 = cWp2; P.cbp2 = cbp2;
  P.cWp3 = cWp3; P.cbp3 = cbp3;
  P.cnt_cfg = cnt_cfg; P.state = state; P.ticket = ticket; P.done = done; P.flag = flag;
  k_init<<<2048, 256, 0, stream>>>(P);

  // 2) CFG CSR
  k_count<<<(E_CFG + 255) / 256, 256, 0, stream>>>(cfg_edges + E_CFG, E_CFG, cnt_cfg);
  k_scan_lb<<<(N_CFG + 1023) / 1024, 256, 0, stream>>>(cnt_cfg, N_CFG, off_cfg, cur_cfg, dis_cfg,
                                                       state, ticket);
  for (int w = 0; w < 2; w++)
    k_fill_win<<<(E_CFG + 255) / 256, 256, 0, stream>>>(cfg_edges, E_CFG, cur_cfg, sorted_cfg,
                                                        w * (N_CFG / 2), (w + 1) * (N_CFG / 2));

  // 3) CFG layer 1: aggregate-first on 64-dim bf16, then GEMM with relu epilogue
  k_aggZ<8><<<N_CFG / 32, 256, 0, stream>>>((const uint4*)cx, off_cfg, cnt_cfg, sorted_cfg,
                                            dis_cfg, (uint4*)A, N_CFG);
  k_gemm_relu<64><<<N_CFG / 64, 256, 0, stream>>>(A, cW1t, dis_cfg, cb1, Bx);

  // 4) CFG layer 2
  k_aggZ<16><<<N_CFG / 16, 256, 0, stream>>>((const uint4*)Bx, off_cfg, cnt_cfg, sorted_cfg,
                                             dis_cfg, (uint4*)A, N_CFG);
  k_gemm_relu<128><<<N_CFG / 64, 256, 0, stream>>>(A, cW2t, dis_cfg, cb2, Bx);

  // 5) per-function pool (binary-search segments) + FCG features
  k_pool_mean<<<N_FUNC, 64, 0, stream>>>((const unsigned int*)Bx, node2func, pooled2);
  k_assemble<<<N_FCG, 64, 0, stream>>>(pooled2, (const unsigned int*)cemb, fcg_src, fcg_isext, fx2);

  // 6) FCG CSR (one block) + FCG layer + pooled head
  k_fcg_csr<<<1, 1024, 0, stream>>>(fcg_edges, cnt_f, off_f, dis_f, sorted_f);
  k_aggZ<16><<<N_FCG / 16, 256, 0, stream>>>((const uint4*)fx2, off_f, cnt_f, sorted_f,
                                             dis_f, (uint4*)Zf, N_FCG);
  k_gemm_relu<128><<<N_FCG / 64, 256, 0, stream>>>(Zf, cWft, dis_f, cbf, yf);
  k_pool_head<<<NBATCH, 256, 0, stream>>>((const uint4*)yf, fcg_batch, G, done,
                                          cWp1, cbp1, cWp2, cbp2, cWp3, cbp3, d_out, flag);
}

// Round 8
// 731.470 us; speedup vs baseline: 1.2013x; 1.2013x over previous
//
#include <hip/hip_runtime.h>
#include <math.h>

#define N_CFG 400000
#define E_CFG 1600000
#define N_FUNC 8000
#define N_EXT 1600
#define N_FCG (N_FUNC + N_EXT)
#define E_FCG 80000
#define NBATCH 8
#define VOCAB 10002

typedef unsigned int uint32;
typedef unsigned long long ull;
typedef __attribute__((ext_vector_type(8))) short bf16x8;
typedef __attribute__((ext_vector_type(4))) float f32x4;

// ---------- bf16 helpers ----------
__device__ __forceinline__ float bf2f(unsigned short u){
  union { unsigned int i; float f; } v; v.i = ((unsigned int)u) << 16; return v.f;
}
__device__ __forceinline__ float bflo(unsigned int u){
  union { unsigned int i; float f; } v; v.i = u << 16; return v.f;
}
__device__ __forceinline__ float bfhi(unsigned int u){
  union { unsigned int i; float f; } v; v.i = u & 0xffff0000u; return v.f;
}
__device__ __forceinline__ unsigned short f2bf(float f){
  union { float f; unsigned int i; } v; v.f = f;
  unsigned int i = v.i;
  unsigned int r = (i + 0x7fffu + ((i >> 16) & 1u)) >> 16;  // RNE
  return (unsigned short)r;
}
__device__ __forceinline__ unsigned int packbf(float x, float y){
  return (unsigned int)f2bf(x) | (((unsigned int)f2bf(y)) << 16);
}
__device__ __forceinline__ int lowerb(const int* __restrict__ a, int n, int key){
  int lo = 0, hi = n;
  while (lo < hi){ int mid = (lo + hi) >> 1; if (a[mid] < key) lo = mid + 1; else hi = mid; }
  return lo;
}

// ---------- k_init: flag + all conversions + zeroing, one kernel ----------
struct InitParams {
  const void *cfg_x, *W1, *W2, *Wf, *b1, *b2, *bfv, *emb, *Wp1, *bp1, *Wp2, *bp2, *Wp3, *bp3;
  unsigned short *cx, *cW1t, *cW2t, *cWft, *cb1, *cb2, *cbf, *cemb, *cWp1, *cbp1, *cWp2, *cbp2, *cWp3, *cbp3;
  uint32 *cnt_cfg; uint32* cnt_f; ull* state; ull* state2; uint32* ticket; uint32* ticket2;
  uint32* done; int* flag;
};

#define CVLOOP(srcp, dstp, nn) \
  for (long i = gid; i < (nn); i += gsz) \
    (dstp)[i] = isbf ? ((const unsigned short*)(srcp))[i] : f2bf(((const float*)(srcp))[i]);

__global__ __launch_bounds__(256)
void k_init(InitParams P){
  __shared__ int viol;
  int tid = threadIdx.x;
  if (tid == 0) viol = 0;
  __syncthreads();
  const unsigned int* eu = (const unsigned int*)P.emb;
  int my = 0;
  for (int i = tid; i < 1024; i += 256){
    unsigned int lo = eu[i] & 0xffffu;
    unsigned int ex = (lo >> 7) & 0xffu;
    if (!((ex == 0u) || (ex >= 80u && ex <= 127u))) my++;
  }
  atomicAdd(&viol, my);
  __syncthreads();
  int isbf = (viol < 100) ? 1 : 0;      // 1 = inputs bf16-packed, 0 = fp32
  long gid = (long)blockIdx.x * 256 + tid;
  long gsz = (long)gridDim.x * 256;
  if (gid == 0){ *P.flag = isbf; *P.ticket = 0u; *P.ticket2 = 0u; *P.done = 0u; }
  for (long i = gid; i < 400; i += gsz) P.state[i] = 0ULL;
  for (long i = gid; i < 16; i += gsz) P.state2[i] = 0ULL;
  uint4 z4 = {0u,0u,0u,0u};
  for (long i = gid; i < N_CFG/4; i += gsz) ((uint4*)P.cnt_cfg)[i] = z4;
  for (long i = gid; i < N_FCG/4; i += gsz) ((uint4*)P.cnt_f)[i] = z4;
  // cfg_x -> canonical bf16 (8 elems / item)
  long nx8 = (long)N_CFG * 64 / 8;
  for (long i = gid; i < nx8; i += gsz){
    uint4 o;
    if (isbf){
      o = ((const uint4*)P.cfg_x)[i];
    } else {
      const float4* f = (const float4*)P.cfg_x + i * 2;
      float4 f0 = f[0], f1 = f[1];
      o.x = packbf(f0.x, f0.y); o.y = packbf(f0.z, f0.w);
      o.z = packbf(f1.x, f1.y); o.w = packbf(f1.z, f1.w);
    }
    ((uint4*)P.cx)[i] = o;
  }
  CVLOOP(P.emb, P.cemb, (long)VOCAB * 128);
  // W transposes (K x 128 -> 128 x K)
  for (long i = gid; i < 64 * 128; i += gsz){
    int k = i >> 7, n = i & 127;
    unsigned short v = isbf ? ((const unsigned short*)P.W1)[i] : f2bf(((const float*)P.W1)[i]);
    P.cW1t[n * 64 + k] = v;
  }
  for (long i = gid; i < 128 * 128; i += gsz){
    int k = i >> 7, n = i & 127;
    unsigned short v = isbf ? ((const unsigned short*)P.W2)[i] : f2bf(((const float*)P.W2)[i]);
    P.cW2t[n * 128 + k] = v;
    unsigned short w = isbf ? ((const unsigned short*)P.Wf)[i] : f2bf(((const float*)P.Wf)[i]);
    P.cWft[n * 128 + k] = w;
  }
  CVLOOP(P.b1, P.cb1, 128); CVLOOP(P.b2, P.cb2, 128); CVLOOP(P.bfv, P.cbf, 128);
  CVLOOP(P.Wp1, P.cWp1, 8192); CVLOOP(P.bp1, P.cbp1, 64);
  CVLOOP(P.Wp2, P.cWp2, 2048); CVLOOP(P.bp2, P.cbp2, 32);
  CVLOOP(P.Wp3, P.cWp3, 32);   CVLOOP(P.bp3, P.cbp3, 1);
}

// ---------- degree count ----------
__global__ void k_count(const int* __restrict__ idx, int n, uint32* __restrict__ cnt){
  int i = blockIdx.x * 256 + threadIdx.x;
  if (i < n) atomicAdd(&cnt[idx[i]], 1u);
}

// ---------- single-kernel exclusive scan (decoupled lookback, ticket-ordered) ----------
__global__ __launch_bounds__(256)
void k_scan_lb(const uint32* __restrict__ cnt, int n,
               uint32* __restrict__ off, uint32* __restrict__ cur, float* __restrict__ dis,
               ull* __restrict__ state, uint32* __restrict__ ticket){
  __shared__ uint32 s[256];
  __shared__ uint32 tshare, bshare;
  int tid = threadIdx.x;
  if (tid == 0) tshare = atomicAdd(ticket, 1u);
  __syncthreads();
  uint32 t = tshare;
  int base = (int)t * 1024 + tid * 4;
  uint32 v0 = (base+0<n)?cnt[base+0]:0u, v1 = (base+1<n)?cnt[base+1]:0u;
  uint32 v2 = (base+2<n)?cnt[base+2]:0u, v3 = (base+3<n)?cnt[base+3]:0u;
  uint32 tsum = v0+v1+v2+v3, x = tsum;
  s[tid] = x; __syncthreads();
  for (int o = 1; o < 256; o <<= 1){
    uint32 y = (tid >= o) ? s[tid - o] : 0u;
    __syncthreads();
    x += y; s[tid] = x; __syncthreads();
  }
  uint32 total = s[255];
  if (tid == 0){
    if (t == 0){
      atomicExch(&state[0], (2ULL << 32) | (ull)total);
      bshare = 0u;
    } else {
      atomicExch(&state[t], (1ULL << 32) | (ull)total);
      uint32 run = 0; int idx = (int)t - 1;
      while (true){
        ull sv = atomicAdd(&state[idx], 0ULL);
        uint32 st = (uint32)(sv >> 32);
        if (st == 0u){ __builtin_amdgcn_s_sleep(1); continue; }
        run += (uint32)sv;
        if (st == 2u) break;
        idx--;
      }
      atomicExch(&state[t], (2ULL << 32) | (ull)(run + total));
      bshare = run;
    }
  }
  __syncthreads();
  uint32 run = bshare + (x - tsum);
  if (base+0<n){ off[base+0]=run; cur[base+0]=run; dis[base+0]=rsqrtf((float)v0+1.f); } run+=v0;
  if (base+1<n){ off[base+1]=run; cur[base+1]=run; dis[base+1]=rsqrtf((float)v1+1.f); } run+=v1;
  if (base+2<n){ off[base+2]=run; cur[base+2]=run; dis[base+2]=rsqrtf((float)v2+1.f); } run+=v2;
  if (base+3<n){ off[base+3]=run; cur[base+3]=run; dis[base+3]=rsqrtf((float)v3+1.f); }
}

// ---------- CSR fill ----------
__global__ void k_fill_win(const int* __restrict__ edges, int E,
                           uint32* __restrict__ cur, int* __restrict__ sorted,
                           int lo, int hi){
  int e = blockIdx.x * 256 + threadIdx.x;
  if (e >= E) return;
  int c = edges[E + e];
  if (c < lo || c >= hi) return;
  int r = edges[e];
  uint32 p = atomicAdd(&cur[c], 1u);
  sorted[p] = r;
}

__global__ void k_fill(const int* __restrict__ edges, int E,
                       uint32* __restrict__ cur, int* __restrict__ sorted){
  int e = blockIdx.x * 256 + threadIdx.x;
  if (e >= E) return;
  int r = edges[e];
  int c = edges[E + e];
  uint32 p = atomicAdd(&cur[c], 1u);
  sorted[p] = r;
}

// ---------- dis-weighted aggregation: Z[n] = sum_in dis[r]*x[r] + dis[n]*x[n] ----------
#define ACCD(u, d) { \
  a[0] = fmaf(d, bflo(u.x), a[0]); a[1] = fmaf(d, bfhi(u.x), a[1]); \
  a[2] = fmaf(d, bflo(u.y), a[2]); a[3] = fmaf(d, bfhi(u.y), a[3]); \
  a[4] = fmaf(d, bflo(u.z), a[4]); a[5] = fmaf(d, bfhi(u.z), a[5]); \
  a[6] = fmaf(d, bflo(u.w), a[6]); a[7] = fmaf(d, bfhi(u.w), a[7]); }

template<int LPN>
__global__ __launch_bounds__(256)
void k_aggZ(const uint4* __restrict__ x4, const uint32* __restrict__ off,
            const uint32* __restrict__ cnt, const int* __restrict__ sorted,
            const float* __restrict__ dis, uint4* __restrict__ z4, int n){
  int tid = threadIdx.x;
  int grp = tid / LPN, sub = tid % LPN;
  int node = blockIdx.x * (256 / LPN) + grp;
  if (node >= n) return;
  uint32 o = off[node], c = cnt[node];
  float a[8] = {0.f,0.f,0.f,0.f,0.f,0.f,0.f,0.f};
  uint32 j = 0;
  for (; j + 3 < c; j += 4){
    int r0 = sorted[o+j], r1 = sorted[o+j+1], r2 = sorted[o+j+2], r3 = sorted[o+j+3];
    float d0 = dis[r0], d1 = dis[r1], d2 = dis[r2], d3 = dis[r3];
    uint4 u0 = x4[(long)r0 * LPN + sub];
    uint4 u1 = x4[(long)r1 * LPN + sub];
    uint4 u2 = x4[(long)r2 * LPN + sub];
    uint4 u3 = x4[(long)r3 * LPN + sub];
    ACCD(u0, d0); ACCD(u1, d1); ACCD(u2, d2); ACCD(u3, d3);
  }
  for (; j < c; j++){
    int r = sorted[o + j];
    float d = dis[r];
    uint4 u = x4[(long)r * LPN + sub];
    ACCD(u, d);
  }
  {
    float d = dis[node];
    uint4 u = x4[(long)node * LPN + sub];
    ACCD(u, d);
  }
  uint4 ov;
  ov.x = packbf(a[0], a[1]); ov.y = packbf(a[2], a[3]);
  ov.z = packbf(a[4], a[5]); ov.w = packbf(a[6], a[7]);
  z4[(long)node * LPN + sub] = ov;
}

// ---------- MFMA GEMM + fused epilogue: out = relu(dis[r]*(Z@W) + bias), N=128 ----------
template<int K>
__global__ __launch_bounds__(256)
void k_gemm_relu(const unsigned short* __restrict__ X, const unsigned short* __restrict__ Wt,
                 const float* __restrict__ dis, const unsigned short* __restrict__ bias,
                 unsigned short* __restrict__ out){
  const int KP = K + 8;
  __shared__ unsigned short Xs[64 * (K + 8)];
  __shared__ unsigned short Ws[128 * (K + 8)];
  int tid = threadIdx.x;
  long row0 = (long)blockIdx.x * 64;
  {
    int n = tid >> 1, half = tid & 1;
    const uint4* src = (const uint4*)(Wt + n * K) + half * (K / 16);
    uint4* dst = (uint4*)(Ws + n * KP) + half * (K / 16);
    #pragma unroll
    for (int i = 0; i < K / 16; i++) dst[i] = src[i];
  }
  {
    int r = tid >> 2, part = tid & 3;
    const uint4* src = (const uint4*)(X + (row0 + r) * K) + part * (K / 32);
    uint4* dst = (uint4*)(Xs + r * KP) + part * (K / 32);
    #pragma unroll
    for (int i = 0; i < K / 32; i++) dst[i] = src[i];
  }
  __syncthreads();

  int w = tid >> 6, lane = tid & 63, m = lane & 15, q = lane >> 4;
  f32x4 acc[8];
  #pragma unroll
  for (int t = 0; t < 8; t++) acc[t] = (f32x4){0.f, 0.f, 0.f, 0.f};
  const unsigned short* Arow = &Xs[(w * 16 + m) * KP + q * 8];
  const unsigned short* Bbase = &Ws[m * KP + q * 8];
  #pragma unroll
  for (int kc = 0; kc < K; kc += 32){
    bf16x8 a = *(const bf16x8*)(Arow + kc);
    #pragma unroll
    for (int t = 0; t < 8; t++){
      bf16x8 b = *(const bf16x8*)(Bbase + t * 16 * KP + kc);
      acc[t] = __builtin_amdgcn_mfma_f32_16x16x32_bf16(a, b, acc[t], 0, 0, 0);
    }
  }
  float d[4];
  #pragma unroll
  for (int r = 0; r < 4; r++) d[r] = dis[row0 + w * 16 + q * 4 + r];
  #pragma unroll
  for (int t = 0; t < 8; t++){
    float bc = bf2f(bias[t * 16 + m]);
    #pragma unroll
    for (int r = 0; r < 4; r++){
      long grow = row0 + w * 16 + q * 4 + r;
      out[grow * 128 + t * 16 + m] = f2bf(fmaxf(fmaf(d[r], acc[t][r], bc), 0.f));
    }
  }
}

// ---------- per-function mean pool, segment bounds via binary search ----------
__global__ void k_pool_mean(const unsigned int* __restrict__ x2, const int* __restrict__ n2f,
                            unsigned int* __restrict__ pooled2){
  int f = blockIdx.x; int t = threadIdx.x;   // 64 threads
  int s = lowerb(n2f, N_CFG, f);
  int e = lowerb(n2f, N_CFG, f + 1);
  float sx = 0.f, sy = 0.f;
  for (int j = s; j < e; j++){
    unsigned int u = x2[(long)j * 64 + t];
    sx += bflo(u); sy += bfhi(u);
  }
  int c = e - s;
  float inv = 1.0f / (float)((c > 0) ? c : 1);
  pooled2[(long)f * 64 + t] = packbf(sx * inv, sy * inv);
}

// ---------- FCG node features ----------
__global__ void k_assemble(const unsigned int* __restrict__ pooled2, const unsigned int* __restrict__ emb2,
                           const int* __restrict__ src, const int* __restrict__ isext,
                           unsigned int* __restrict__ fx2){
  int i = blockIdx.x; int t = threadIdx.x;
  int s = src[i];
  unsigned int v;
  if (isext[i] == 1){
    int idx = s; if (idx < 0) idx = 0; if (idx > VOCAB - 1) idx = VOCAB - 1;
    v = emb2[(long)idx * 64 + t];
  } else {
    int f = s; if (f < 0) f = 0; if (f > N_FUNC - 1) f = N_FUNC - 1;
    v = pooled2[(long)f * 64 + t];
  }
  fx2[(long)i * 64 + t] = v;
}

// ---------- per-binary mean pool + head (last-block pattern, device-scope atomics) ----------
__global__ __launch_bounds__(256)
void k_pool_head(const uint4* __restrict__ y4, const int* __restrict__ batch,
                 float* __restrict__ G, uint32* __restrict__ done,
                 const unsigned short* __restrict__ Wp1, const unsigned short* __restrict__ bp1,
                 const unsigned short* __restrict__ Wp2, const unsigned short* __restrict__ bp2,
                 const unsigned short* __restrict__ Wp3, const unsigned short* __restrict__ bp3,
                 void* __restrict__ outp, const int* __restrict__ flag){
  __shared__ float red[16][128];
  __shared__ uint32 tick;
  int b = blockIdx.x, tid = threadIdx.x;
  int s = lowerb(batch, N_FCG, b);
  int e = lowerb(batch, N_FCG, b + 1);
  int grp = tid >> 4, sub = tid & 15;
  float a[8] = {0.f,0.f,0.f,0.f,0.f,0.f,0.f,0.f};
  for (int i = s + grp; i < e; i += 16){
    uint4 u = y4[(long)i * 16 + sub];
    a[0] += bflo(u.x); a[1] += bfhi(u.x);
    a[2] += bflo(u.y); a[3] += bfhi(u.y);
    a[4] += bflo(u.z); a[5] += bfhi(u.z);
    a[6] += bflo(u.w); a[7] += bfhi(u.w);
  }
  #pragma unroll
  for (int i = 0; i < 8; i++) red[grp][sub * 8 + i] = a[i];
  __syncthreads();
  int c = e - s;
  float inv = 1.0f / (float)((c > 0) ? c : 1);
  if (tid < 128){
    float t2 = 0.f;
    #pragma unroll
    for (int g = 0; g < 16; g++) t2 += red[g][tid];
    atomicExch((unsigned int*)&G[b * 128 + tid], __float_as_uint(t2 * inv));
  }
  __threadfence();
  __syncthreads();
  if (tid == 0) tick = atomicAdd(done, 1u);
  __syncthreads();
  if (tick != NBATCH - 1) return;
  __shared__ float Gs[1024];
  __shared__ float H1[512];
  __shared__ float H2[256];
  for (int i = tid; i < 1024; i += 256)
    Gs[i] = __uint_as_float(atomicAdd((unsigned int*)&G[i], 0u));
  __syncthreads();
  for (int i = tid; i < 512; i += 256){
    int bb = i >> 6, j = i & 63;
    float acc = bf2f(bp1[j]);
    for (int d = 0; d < 128; d++) acc = fmaf(Gs[bb * 128 + d], bf2f(Wp1[d * 64 + j]), acc);
    H1[i] = fmaxf(acc, 0.f);
  }
  __syncthreads();
  {
    int bb = tid >> 5, j = tid & 31;
    float acc = bf2f(bp2[j]);
    for (int d = 0; d < 64; d++) acc = fmaf(H1[bb * 64 + d], bf2f(Wp2[d * 32 + j]), acc);
    H2[tid] = fmaxf(acc, 0.f);
  }
  __syncthreads();
  if (tid < 8){
    float acc = bf2f(bp3[0]);
    for (int d = 0; d < 32; d++) acc = fmaf(H2[tid * 32 + d], bf2f(Wp3[d]), acc);
    float sg = 1.f / (1.f + __expf(-acc));
    if (*flag) ((unsigned short*)outp)[tid] = f2bf(sg);
    else       ((float*)outp)[tid] = sg;
  }
}

extern "C" void kernel_launch(void* const* d_in, const int* in_sizes, int n_in,
                              void* d_out, int out_size, void* d_ws, size_t ws_size,
                              hipStream_t stream){
  const void* cfg_x     = d_in[0];
  const int*  cfg_edges = (const int*)d_in[1];
  const int*  node2func = (const int*)d_in[2];
  const int*  fcg_edges = (const int*)d_in[3];
  const int*  fcg_batch = (const int*)d_in[4];
  const int*  fcg_src   = (const int*)d_in[5];
  const int*  fcg_isext = (const int*)d_in[6];

  char* p = (char*)d_ws;
  auto carve = [&](size_t bytes)->char* {
    char* r = p; p += (bytes + 255) & ~(size_t)255; return r;
  };
  unsigned short* A   = (unsigned short*)carve((size_t)N_CFG * 128 * 2);  // Z1 / Z2
  unsigned short* Bx  = (unsigned short*)carve((size_t)N_CFG * 128 * 2);  // x2 / x3
  unsigned short* cx  = (unsigned short*)carve((size_t)N_CFG * 64 * 2);   // canonical bf16 cfg_x
  uint32* cnt_cfg = (uint32*)carve((size_t)N_CFG * 4);
  uint32* off_cfg = (uint32*)carve((size_t)N_CFG * 4);
  uint32* cur_cfg = (uint32*)carve((size_t)N_CFG * 4);
  float*  dis_cfg = (float*) carve((size_t)N_CFG * 4);
  int*    sorted_cfg = (int*)carve((size_t)E_CFG * 4);
  ull*    state  = (ull*)carve(400 * 8);
  ull*    state2 = (ull*)carve(16 * 8);
  uint32* ticket = (uint32*)carve(256);
  uint32* ticket2= (uint32*)carve(256);
  uint32* done   = (uint32*)carve(256);
  int*    flag   = (int*)carve(256);
  unsigned int* pooled2 = (unsigned int*)carve((size_t)N_FUNC * 64 * 4);
  unsigned int* fx2     = (unsigned int*)carve((size_t)N_FCG * 64 * 4);
  unsigned short* Zf    = (unsigned short*)carve((size_t)N_FCG * 128 * 2);
  unsigned short* yf    = (unsigned short*)carve((size_t)N_FCG * 128 * 2);
  uint32* cnt_f = (uint32*)carve(N_FCG * 4);
  uint32* off_f = (uint32*)carve(N_FCG * 4);
  uint32* cur_f = (uint32*)carve(N_FCG * 4);
  float*  dis_f = (float*) carve(N_FCG * 4);
  int*    sorted_f = (int*)carve(E_FCG * 4);
  float*  G = (float*)carve(8 * 128 * 4);
  unsigned short* cW1t = (unsigned short*)carve(128 * 64 * 2);
  unsigned short* cb1  = (unsigned short*)carve(128 * 2);
  unsigned short* cW2t = (unsigned short*)carve(128 * 128 * 2);
  unsigned short* cb2  = (unsigned short*)carve(128 * 2);
  unsigned short* cemb = (unsigned short*)carve((size_t)VOCAB * 128 * 2);
  unsigned short* cWft = (unsigned short*)carve(128 * 128 * 2);
  unsigned short* cbf  = (unsigned short*)carve(128 * 2);
  unsigned short* cWp1 = (unsigned short*)carve(128 * 64 * 2);
  unsigned short* cbp1 = (unsigned short*)carve(64 * 2);
  unsigned short* cWp2 = (unsigned short*)carve(64 * 32 * 2);
  unsigned short* cbp2 = (unsigned short*)carve(32 * 2);
  unsigned short* cWp3 = (unsigned short*)carve(32 * 2);
  unsigned short* cbp3 = (unsigned short*)carve(2 * 2);

  // 1) init: flag + conversions + zeroing
  InitParams P;
  P.cfg_x = cfg_x; P.W1 = d_in[7]; P.W2 = d_in[9]; P.Wf = d_in[12];
  P.b1 = d_in[8]; P.b2 = d_in[10]; P.bfv = d_in[13]; P.emb = d_in[11];
  P.Wp1 = d_in[14]; P.bp1 = d_in[15]; P.Wp2 = d_in[16]; P.bp2 = d_in[17];
  P.Wp3 = d_in[18]; P.bp3 = d_in[19];
  P.cx = cx; P.cW1t = cW1t; P.cW2t = cW2t; P.cWft = cWft;
  P.cb1 = cb1; P.cb2 = cb2; P.cbf = cbf; P.cemb = cemb;
  P.cWp1 = cWp1; P.cbp1 = cbp1; P.cWp2 = cWp2; P.cbp2 = cbp2;
  P.cWp3 = cWp3; P.cbp3 = cbp3;
  P.cnt_cfg = cnt_cfg; P.cnt_f = cnt_f; P.state = state; P.state2 = state2;
  P.ticket = ticket; P.ticket2 = ticket2; P.done = done; P.flag = flag;
  k_init<<<2048, 256, 0, stream>>>(P);

  // 2) CFG CSR
  k_count<<<(E_CFG + 255) / 256, 256, 0, stream>>>(cfg_edges + E_CFG, E_CFG, cnt_cfg);
  k_scan_lb<<<(N_CFG + 1023) / 1024, 256, 0, stream>>>(cnt_cfg, N_CFG, off_cfg, cur_cfg, dis_cfg,
                                                       state, ticket);
  for (int w = 0; w < 2; w++)
    k_fill_win<<<(E_CFG + 255) / 256, 256, 0, stream>>>(cfg_edges, E_CFG, cur_cfg, sorted_cfg,
                                                        w * (N_CFG / 2), (w + 1) * (N_CFG / 2));

  // 3) CFG layer 1: aggregate-first on 64-dim bf16, then GEMM with relu epilogue
  k_aggZ<8><<<N_CFG / 32, 256, 0, stream>>>((const uint4*)cx, off_cfg, cnt_cfg, sorted_cfg,
                                            dis_cfg, (uint4*)A, N_CFG);
  k_gemm_relu<64><<<N_CFG / 64, 256, 0, stream>>>(A, cW1t, dis_cfg, cb1, Bx);

  // 4) CFG layer 2
  k_aggZ<16><<<N_CFG / 16, 256, 0, stream>>>((const uint4*)Bx, off_cfg, cnt_cfg, sorted_cfg,
                                             dis_cfg, (uint4*)A, N_CFG);
  k_gemm_relu<128><<<N_CFG / 64, 256, 0, stream>>>(A, cW2t, dis_cfg, cb2, Bx);

  // 5) per-function pool (binary-search segments) + FCG features
  k_pool_mean<<<N_FUNC, 64, 0, stream>>>((const unsigned int*)Bx, node2func, pooled2);
  k_assemble<<<N_FCG, 64, 0, stream>>>(pooled2, (const unsigned int*)cemb, fcg_src, fcg_isext, fx2);

  // 6) FCG CSR — wide small kernels (single-block LDS version was 169us: 1 CU + LDS-atomic serial)
  k_count<<<(E_FCG + 255) / 256, 256, 0, stream>>>(fcg_edges + E_FCG, E_FCG, cnt_f);
  k_scan_lb<<<(N_FCG + 1023) / 1024, 256, 0, stream>>>(cnt_f, N_FCG, off_f, cur_f, dis_f,
                                                       state2, ticket2);
  k_fill<<<(E_FCG + 255) / 256, 256, 0, stream>>>(fcg_edges, E_FCG, cur_f, sorted_f);

  // 7) FCG layer + pooled head
  k_aggZ<16><<<N_FCG / 16, 256, 0, stream>>>((const uint4*)fx2, off_f, cnt_f, sorted_f,
                                             dis_f, (uint4*)Zf, N_FCG);
  k_gemm_relu<128><<<N_FCG / 64, 256, 0, stream>>>(Zf, cWft, dis_f, cbf, yf);
  k_pool_head<<<NBATCH, 256, 0, stream>>>((const uint4*)yf, fcg_batch, G, done,
                                          cWp1, cbp1, cWp2, cbp2, cWp3, cbp3, d_out, flag);
}